// Round 4
// baseline (71.536 us; speedup 1.0000x reference)
//
#include <hip/hip_runtime.h>

// Shapes fixed by the reference: bs=4, n=10, H=W=256.
constexpr int kN  = 10;        // planes
constexpr int kHW = 256 * 256;
constexpr int kBS = 4;

typedef float v2f __attribute__((ext_vector_type(2)));

// One thread per pixel (262,144 threads, 1024 blocks). Adjacent splits
// (i, i+1) are evaluated together in packed-f32 (v_pk_add/mul_f32): each
// half of every packed op is exactly the reference's scalar op on the
// reference's values in the reference's association, so bit-exactness
// (absmax == 0.0 since R1) is preserved.
//
// Bit-exactness contract:
//  * plane sums: left-associative sequential adds, prefix-shared with the
//    SAME association as the reference fold (verified absmax 0.0 R2/R3).
//  * x/10, x/9: (float)((double)x * RN(1/10 or 1/9)) — proven identical to
//    correctly-rounded fp32 division (f64 product rel-err <= 2.3e-16 vs
//    >= ~8e-10 distance of any quotient to an fp32 rounding midpoint).
//  * (v-mean)^2: separate sub/mul/add under fp contract(off) — no FMA.
//  * sqrtf: correctly-rounded fp32 sqrt (default HIP, no fast-math).
//  * argmin: strict <, split i checked before i+1 — first occurrence.
// DO NOT switch argmin to variance or drop the CR-sqrt: sds that tie after
// rounding but differ in var would flip first-occurrence (~O(1) expected
// pixels at 262k), costing up to 2*blur/n ~ 0.2 vs threshold 3.8e-2.
__global__ __launch_bounds__(256) void distreg_kernel(
    const float* __restrict__ s1, const float* __restrict__ blur,
    float* __restrict__ out) {
  #pragma clang fp contract(off)
  const int g = blockIdx.x * blockDim.x + threadIdx.x;  // pixel id
  const int b = g >> 16;        // kHW == 65536
  const int r = g & (kHW - 1);

  const long base = (long)b * kN * kHW + r;

  float lo[kN], hi[kN];
  #pragma unroll
  for (int j = 0; j < kN; ++j) {
    const float s  = s1[base + (long)j * kHW];
    const float bl = blur[base + (long)j * kHW];
    lo[j] = s - bl;   // used for j >= split i
    hi[j] = s + bl;   // used for j <  split i
  }

  float best_sd   = __builtin_inff();
  float best_mean = 0.0f;

  float p_lo = 0.0f;  // p_i = ((hi[0]+hi[1])+...)+hi[i-1], sequential
  #pragma unroll
  for (int i = 0; i < kN; i += 2) {
    const float p_hi_ = p_lo + hi[i];      // p_{i+1}

    // sum.x = ((p_i + lo[i]) + lo[i+1]) + ... + lo[9]
    // sum.y = (p_{i+1} + lo[i+1]) + ... + lo[9]
    v2f sum;
    sum.x = p_lo + lo[i];
    sum.y = p_hi_;
    #pragma unroll
    for (int j = i + 1; j < kN; ++j) {
      const v2f bj = {lo[j], lo[j]};
      sum = sum + bj;                      // v_pk_add_f32
    }
    const float mean_a = (float)((double)sum.x * 0.1);       // == /10.0f
    const float mean_b = (float)((double)sum.y * 0.1);
    const v2f mean = {mean_a, mean_b};

    v2f sq = {0.0f, 0.0f};
    #pragma unroll
    for (int j = 0; j < kN; ++j) {
      v2f v;
      if (j < i)       v = (v2f){hi[j], hi[j]};   // both splits: hi
      else if (j == i) v = (v2f){lo[i], hi[i]};   // split i: lo, split i+1: hi
      else             v = (v2f){lo[j], lo[j]};   // both splits: lo
      const v2f x  = v - mean;                    // v_pk_add_f32 (neg)
      const v2f xx = x * x;                       // v_pk_mul_f32, no contract
      sq = sq + xx;                               // v_pk_add_f32
    }
    const float var_a = (float)((double)sq.x * (1.0 / 9.0));  // == /9.0f
    const float var_b = (float)((double)sq.y * (1.0 / 9.0));
    const float sd_a = sqrtf(var_a);
    const float sd_b = sqrtf(var_b);
    // split i strictly before i+1: preserves first-occurrence argmin.
    if (sd_a < best_sd) { best_sd = sd_a; best_mean = mean_a; }
    if (sd_b < best_sd) { best_sd = sd_b; best_mean = mean_b; }

    p_lo = p_hi_ + hi[i + 1];              // p_{i+2}, sequential association
  }

  // split i == 10: all planes use hi; sum_10 == p_10 (no extra adds).
  {
    const float mean = (float)((double)p_lo * 0.1);
    float sq = 0.0f;
    #pragma unroll
    for (int j = 0; j < kN; ++j) {
      const float x  = hi[j] - mean;
      const float xx = x * x;
      sq = sq + xx;
    }
    const float var = (float)((double)sq * (1.0 / 9.0));
    const float sd  = sqrtf(var);
    if (sd < best_sd) { best_sd = sd; best_mean = mean; }
  }

  out[(long)b * kHW + r] = best_mean;
}

extern "C" void kernel_launch(void* const* d_in, const int* in_sizes, int n_in,
                              void* d_out, int out_size, void* d_ws, size_t ws_size,
                              hipStream_t stream) {
  const float* s1   = (const float*)d_in[0];
  const float* blur = (const float*)d_in[1];
  float* out = (float*)d_out;

  const int total = kBS * kHW;            // 262,144 pixels
  const int block = 256;
  const int grid  = total / block;        // 1024 blocks
  distreg_kernel<<<grid, block, 0, stream>>>(s1, blur, out);
}